// Round 7
// baseline (510.553 us; speedup 1.0000x reference)
//
#include <hip/hip_runtime.h>
#include <math.h>

// N=4, S=2048, D=1024, fp32 in/out.
// Pipeline (ALL GEMMs GLL-staged f16-plane MFMA; f32->f16 split happens once, pre-pass):
//   split3  : {q,k,v} -> planes (q,k hi/lo; v hi) ; {WQ,WK,WV} -> planes
//   wq = q@WQt, wk = k@WKt : triple-product (hh+hl+lh) GLL GEMM, split-plane out
//   wvT = (v@WVt)^T        : single-product GLL GEMM, f16 hi transposed out [n][o][s]
//   Sc = wq@wkt            : triple GLL GEMM, f32 out + fused column-stat partials
//   combine                : fold 16 q-chunk partials -> m[k], r[k]=1/sum
//   out = (P @ wvT^T)/1024 : single-product GEMM; A staged as raw f32 Sc via GLL,
//                            P = exp(Sc-m[k])*r[k] computed at the LDS->fragment read
// Workspace (f16 units, NSD = 8388608, DD = 1048576):
//   [0,1)N      q_hi   ; later wvT_hi (q dead after q-proj)
//   [1,2)N      q_lo   ; later Sc f32 spans [1,5)N (q_lo/k/v dead by then; live thru final)
//   [2,4)N      k_hi|k_lo
//   [4,5)N      v_hi
//   [5N,5N+5DD) WQ_hi|WQ_lo|WK_hi|WK_lo|WV_hi
//   [5N+5DD, 9N+5DD) wq_hi|wq_lo|wk_hi|wk_lo  (dead after scores)
//   [9N+5DD, ..) stats (pm|ps|statM|statR, ~1.1 MB)

typedef _Float16 f16;
typedef _Float16 f16x8 __attribute__((ext_vector_type(8)));
typedef float f32x4 __attribute__((ext_vector_type(4)));

enum StageMode { SM_PLANES2, SM_PLANES1, SM_EXPF32 };
enum EpiMode   { EPI_F32, EPI_SPLIT, EPI_F16T };

#define GLL_PITCH 32   // f16 units/row; unpadded, XOR-swizzled 16B chunks

// async global->LDS, 16B per lane; LDS dest = wave-uniform base + lane*16
__device__ __forceinline__ void gll16(const void* g, void* l) {
    __builtin_amdgcn_global_load_lds(
        (const __attribute__((address_space(1))) void*)g,
        (__attribute__((address_space(3))) void*)l, 16, 0, 0);
}

// Stage one 128x32 f16 plane via GLL with XOR chunk swizzle.
// Physical 16B slot t holds data (row = t>>2, chunk = (t&3) ^ ((row>>1)&3)).
__device__ __forceinline__ void stage_gll_plane(const f16* __restrict__ gplane,
                                                f16* __restrict__ lds,
                                                long rowBase, int ld, int k0,
                                                int wave, int lane)
{
#pragma unroll
    for (int i = 0; i < 2; i++) {
        int slotBase = (wave * 2 + i) * 64;
        int t = slotBase + lane;
        int r = t >> 2;
        int c = (t & 3) ^ ((r >> 1) & 3);
        const f16* g = gplane + (rowBase + r) * (long)ld + k0 + c * 8;
        gll16(g, lds + (long)slotBase * 8);   // wave-uniform LDS base
    }
}

// Stage one 128x32 f32 tile (16 KB) via GLL. Row = 128 B = 8 chunks of 16 B.
// Physical slot t holds (row = t>>3, logical chunk = (t&7) ^ (row&7)).
__device__ __forceinline__ void stage_gll_f32(const float* __restrict__ gplane,
                                              float* __restrict__ lds,
                                              long rowBase, int ld, int k0,
                                              int wave, int lane)
{
#pragma unroll
    for (int i = 0; i < 4; i++) {
        int slotBase = (wave * 4 + i) * 64;
        int t = slotBase + lane;
        int r = t >> 3;
        int lc = (t & 7) ^ (r & 7);
        const float* g = gplane + (rowBase + r) * (long)ld + k0 + lc * 4;
        gll16(g, lds + (long)slotBase * 4);   // wave-uniform LDS base
    }
}

__device__ __forceinline__ int frag_off_gll(int row, int g) {
    return row * GLL_PITCH + ((g ^ ((row >> 1) & 3)) << 3);
}

// C = A * B^T. A: [M,K], B: [Nc,K] row-major (per batch plane).
// Tile 128x128, BK=32, 256 threads = 4 waves, each wave 64x64 (4x4 of 16x16x32).
template<StageMode SA, StageMode SB, EpiMode EP, int GROUPM, bool STATS, int LB>
__global__ __launch_bounds__(256, LB)
void mfma_gemm(const void* __restrict__ Ahi, const void* __restrict__ Alo,
               const void* __restrict__ Bhi, const void* __restrict__ Blo,
               const float* __restrict__ statM, const float* __restrict__ statR,
               float* __restrict__ pmOut, float* __restrict__ psOut,
               void* __restrict__ C0, void* __restrict__ C1,
               int M, int Nc, int K, int lda, int ldb, int ldc,
               long batchA, long batchB, long batchC,
               float epiScale, int tsShift)
{
    constexpr bool TRIPLE = (SA == SM_PLANES2);
    constexpr int PLANE_SZ = 128 * GLL_PITCH;      // f16 units (8 KB)
    constexpr bool A_F32 = (SA == SM_EXPF32);

    int bx, by;
    if constexpr (GROUPM > 0) {
        int gx = gridDim.x;
        int lin = blockIdx.y * gx + blockIdx.x;
        int nig = GROUPM * gx;
        int gid = lin / nig;
        int rem = lin - gid * nig;
        by = gid * GROUPM + (rem % GROUPM);
        bx = rem / GROUPM;
    } else {
        bx = blockIdx.x;
        by = blockIdx.y;
    }
    const int n0 = bx * 128;
    const int m0 = by * 128;
    const long z = blockIdx.z;

    const long aOfs = z * batchA, bOfs = z * batchB, cOfs = z * batchC;

    __shared__ __align__(16) f16 As_hi[A_F32 ? 2 * PLANE_SZ : PLANE_SZ];  // f32 tile = 16 KB
    __shared__ __align__(16) f16 Bs_hi[PLANE_SZ];
    __shared__ __align__(16) f16 As_lo[TRIPLE ? PLANE_SZ : 8];
    __shared__ __align__(16) f16 Bs_lo[TRIPLE ? PLANE_SZ : 8];

    const int tid  = threadIdx.x;
    const int lane = tid & 63;
    const int wave = tid >> 6;
    const int wr = (wave >> 1) * 64;
    const int wc = (wave & 1) * 64;
    const int fm = lane & 15;
    const int fg = lane >> 4;        // k-chunk index 0..3

    f32x4 acc[4][4];
#pragma unroll
    for (int i = 0; i < 4; i++)
#pragma unroll
        for (int j = 0; j < 4; j++) acc[i][j] = (f32x4){0.f, 0.f, 0.f, 0.f};

    int roA[4], roB[4];
#pragma unroll
    for (int i = 0; i < 4; i++) {
        roA[i] = frag_off_gll(wr + i * 16 + fm, fg);
        roB[i] = frag_off_gll(wc + i * 16 + fm, fg);
    }

    for (int k0 = 0; k0 < K; k0 += 32) {
        // ---- stage A ----
        if constexpr (A_F32) {
            stage_gll_f32((const float*)Ahi + aOfs, (float*)As_hi, m0, lda, k0, wave, lane);
        } else {
            stage_gll_plane((const f16*)Ahi + aOfs, As_hi, m0, lda, k0, wave, lane);
            if constexpr (TRIPLE)
                stage_gll_plane((const f16*)Alo + aOfs, As_lo, m0, lda, k0, wave, lane);
        }
        // ---- stage B ----
        stage_gll_plane((const f16*)Bhi + bOfs, Bs_hi, n0, ldb, k0, wave, lane);
        if constexpr (TRIPLE)
            stage_gll_plane((const f16*)Blo + bOfs, Bs_lo, n0, ldb, k0, wave, lane);
        __syncthreads();

        f16x8 ah[4], bh[4], al[4], bl[4];
        if constexpr (A_F32) {
            // P = exp(Sc - M[k]) * R[k] at fragment read; stats indexed by k (K-dim)
            const float* pM = statM + z * (long)K;
            const float* pR = statR + z * (long)K;
            float4 Ma = *(const float4*)&pM[k0 + fg * 8];
            float4 Mb = *(const float4*)&pM[k0 + fg * 8 + 4];
            float4 Ra = *(const float4*)&pR[k0 + fg * 8];
            float4 Rb = *(const float4*)&pR[k0 + fg * 8 + 4];
            const float* Asf = (const float*)As_hi;
            const int p0 = (fg << 1) ^ (fm & 7);   // ra&7 == fm&7 (wr, i*16 are mult of 8)
#pragma unroll
            for (int i = 0; i < 4; i++) {
                int ra = wr + i * 16 + fm;
                float4 xa = *(const float4*)&Asf[ra * 32 + p0 * 4];
                float4 xb = *(const float4*)&Asf[ra * 32 + (p0 ^ 1) * 4];
                f16x8 h;
                h[0] = (f16)(__expf(xa.x - Ma.x) * Ra.x);
                h[1] = (f16)(__expf(xa.y - Ma.y) * Ra.y);
                h[2] = (f16)(__expf(xa.z - Ma.z) * Ra.z);
                h[3] = (f16)(__expf(xa.w - Ma.w) * Ra.w);
                h[4] = (f16)(__expf(xb.x - Mb.x) * Rb.x);
                h[5] = (f16)(__expf(xb.y - Mb.y) * Rb.y);
                h[6] = (f16)(__expf(xb.z - Mb.z) * Rb.z);
                h[7] = (f16)(__expf(xb.w - Mb.w) * Rb.w);
                ah[i] = h;
            }
        } else {
#pragma unroll
            for (int i = 0; i < 4; i++) {
                ah[i] = *(const f16x8*)&As_hi[roA[i]];
                if constexpr (TRIPLE) al[i] = *(const f16x8*)&As_lo[roA[i]];
            }
        }
#pragma unroll
        for (int i = 0; i < 4; i++) {
            bh[i] = *(const f16x8*)&Bs_hi[roB[i]];
            if constexpr (TRIPLE) bl[i] = *(const f16x8*)&Bs_lo[roB[i]];
        }
#pragma unroll
        for (int i = 0; i < 4; i++) {
#pragma unroll
            for (int j = 0; j < 4; j++) {
                acc[i][j] = __builtin_amdgcn_mfma_f32_16x16x32_f16(ah[i], bh[j], acc[i][j], 0, 0, 0);
                if constexpr (TRIPLE) {
                    acc[i][j] = __builtin_amdgcn_mfma_f32_16x16x32_f16(ah[i], bl[j], acc[i][j], 0, 0, 0);
                    acc[i][j] = __builtin_amdgcn_mfma_f32_16x16x32_f16(al[i], bh[j], acc[i][j], 0, 0, 0);
                }
            }
        }
        __syncthreads();
    }

    // Epilogue. C/D frag: col = lane&15, row = (lane>>4)*4 + reg  [m89-verified]
    const int cr = fg * 4;
    const int cn = fm;
#pragma unroll
    for (int i = 0; i < 4; i++) {
#pragma unroll
        for (int j = 0; j < 4; j++) {
#pragma unroll
            for (int r = 0; r < 4; r++) {
                long mg = m0 + wr + i * 16 + cr + r;
                long ng = n0 + wc + j * 16 + cn;
                float val = acc[i][j][r] * epiScale;
                if constexpr (EP == EPI_F32) {
                    ((float*)C0)[cOfs + mg * ldc + ng] = val;
                } else if constexpr (EP == EPI_SPLIT) {
                    f16 h = (f16)val;
                    ((f16*)C0)[cOfs + mg * ldc + ng] = h;
                    ((f16*)C1)[cOfs + mg * ldc + ng] = (f16)(val - (float)h);
                } else { // EPI_F16T: batch folded in M; write [nb][n][s], hi only
                    long TS = 1L << tsShift;
                    long nb = mg >> tsShift;
                    long s  = mg & (TS - 1);
                    long addr = nb * ((long)Nc << tsShift) + ng * TS + s;
                    ((f16*)C0)[addr] = (f16)val;
                }
            }
        }
    }

    // Fused column-softmax partials over this tile's 128 rows (q). epiScale==1 required.
    if constexpr (STATS) {
        __shared__ float stM[2][128];
        __shared__ float stS[2][128];
#pragma unroll
        for (int j = 0; j < 4; j++) {
            float mj = -3.402823466e38f;
#pragma unroll
            for (int i = 0; i < 4; i++)
#pragma unroll
                for (int r = 0; r < 4; r++) mj = fmaxf(mj, acc[i][j][r]);
            float sj = 0.f;
#pragma unroll
            for (int i = 0; i < 4; i++)
#pragma unroll
                for (int r = 0; r < 4; r++) sj += __expf(acc[i][j][r] - mj);
#pragma unroll
            for (int mask = 16; mask <= 32; mask <<= 1) {
                float mo = __shfl_xor(mj, mask, 64);
                float so = __shfl_xor(sj, mask, 64);
                float mn = fmaxf(mj, mo);
                sj = sj * __expf(mj - mn) + so * __expf(mo - mn);
                mj = mn;
            }
            if (fg == 0) {
                stM[wave >> 1][wc + j * 16 + cn] = mj;
                stS[wave >> 1][wc + j * 16 + cn] = sj;
            }
        }
        __syncthreads();
        if (tid < 128) {
            float ma = stM[0][tid], mb = stM[1][tid];
            float Mc = fmaxf(ma, mb);
            float Sv = stS[0][tid] * __expf(ma - Mc) + stS[1][tid] * __expf(mb - Mc);
            long o = ((long)z * (M >> 7) + by) * (long)Nc + (long)bx * 128 + tid;
            pmOut[o] = Mc;
            psOut[o] = Sv;
        }
    }
}

// Split 3 f32 arrays into f16 hi (+lo for first two). grid.y selects the array.
__global__ __launch_bounds__(256)
void split3_kernel(const float* __restrict__ s0, const float* __restrict__ s1,
                   const float* __restrict__ s2,
                   f16* __restrict__ h0, f16* __restrict__ l0,
                   f16* __restrict__ h1, f16* __restrict__ l1,
                   f16* __restrict__ h2, long n)
{
    const int which = blockIdx.y;
    const float* src = which == 0 ? s0 : which == 1 ? s1 : s2;
    f16* hi = which == 0 ? h0 : which == 1 ? h1 : h2;
    f16* lo = which == 0 ? l0 : which == 1 ? l1 : nullptr;
    long i = ((long)blockIdx.x * 256 + threadIdx.x) * 8;
    if (i >= n) return;
    float4 x0 = *(const float4*)&src[i];
    float4 x1 = *(const float4*)&src[i + 4];
    float xs[8] = {x0.x, x0.y, x0.z, x0.w, x1.x, x1.y, x1.z, x1.w};
    f16x8 h, l;
#pragma unroll
    for (int e = 0; e < 8; e++) {
        f16 hh = (f16)xs[e];
        h[e] = hh;
        l[e] = (f16)(xs[e] - (float)hh);
    }
    *(f16x8*)&hi[i] = h;
    if (lo) *(f16x8*)&lo[i] = l;
}

// Fold the 16 q-chunk partials -> m[k], r[k] = 1/sum.
__global__ __launch_bounds__(64)
void stats_combine_kernel(const float* __restrict__ pm, const float* __restrict__ ps,
                          float* __restrict__ statM, float* __restrict__ statR, int S)
{
    const int n = blockIdx.y;
    const int kk = blockIdx.x * 64 + threadIdx.x;
    float M = -INFINITY;
#pragma unroll
    for (int i = 0; i < 16; i++)
        M = fmaxf(M, pm[((long)n * 16 + i) * S + kk]);
    float Ssum = 0.f;
#pragma unroll
    for (int i = 0; i < 16; i++)
        Ssum += ps[((long)n * 16 + i) * S + kk] * __expf(pm[((long)n * 16 + i) * S + kk] - M);
    statM[(long)n * S + kk] = M;
    statR[(long)n * S + kk] = 1.0f / Ssum;
}

extern "C" void kernel_launch(void* const* d_in, const int* in_sizes, int n_in,
                              void* d_out, int out_size, void* d_ws, size_t ws_size,
                              hipStream_t stream)
{
    const float* v  = (const float*)d_in[0];
    const float* k  = (const float*)d_in[1];
    const float* q  = (const float*)d_in[2];
    const float* WV = (const float*)d_in[3];
    const float* WQ = (const float*)d_in[4];
    const float* WK = (const float*)d_in[5];
    float* out = (float*)d_out;

    const int N = 4, S = 2048, D = 1024;
    const long NSD = (long)N * S * D;   // 8388608
    const long DD  = (long)D * D;       // 1048576

    f16* ws = (f16*)d_ws;
    f16* q_hi = ws;                 // [0,1)N
    f16* q_lo = ws + NSD;           // [1,2)N
    f16* k_hi = ws + 2 * NSD;
    f16* k_lo = ws + 3 * NSD;
    f16* v_hi = ws + 4 * NSD;
    f16* Wb   = ws + 5 * NSD;
    f16* WQ_hi = Wb,          *WQ_lo = Wb + DD;
    f16* WK_hi = Wb + 2 * DD, *WK_lo = Wb + 3 * DD;
    f16* WV_hi = Wb + 4 * DD;
    f16* wq_hi = ws + 5 * NSD + 5 * DD;
    f16* wq_lo = wq_hi + NSD;
    f16* wk_hi = wq_hi + 2 * NSD;
    f16* wk_lo = wq_hi + 3 * NSD;
    // aliases (lifetime-checked):
    f16* wvT_hi = ws;                       // [0,1)N — q_hi dead after q-proj
    float* Sc   = (float*)(ws + NSD);       // [1,5)N — q_lo/k/v dead by scores; live thru final
    // stats
    float* pm    = (float*)(ws + 9 * NSD + 5 * DD);   // [N][16][S]
    float* ps    = pm + (long)N * 16 * S;
    float* statM = ps + (long)N * 16 * S;
    float* statR = statM + (long)N * S;

    dim3 blk(256);

    // ---- split pre-pass: 2 launches ----
    split3_kernel<<<dim3(NSD / 2048, 3), blk, 0, stream>>>(
        q, k, v, q_hi, q_lo, k_hi, k_lo, v_hi, NSD);
    split3_kernel<<<dim3(DD / 2048, 3), blk, 0, stream>>>(
        WQ, WK, WV, WQ_hi, WQ_lo, WK_hi, WK_lo, WV_hi, DD);

    // ---- projections: M = N*S folded, C = X @ W^T ----
    {
        dim3 g(D / 128, (N * S) / 128, 1);
        mfma_gemm<SM_PLANES2, SM_PLANES2, EPI_SPLIT, 4, false, 4><<<g, blk, 0, stream>>>(
            q_hi, q_lo, WQ_hi, WQ_lo, nullptr, nullptr, nullptr, nullptr, wq_hi, wq_lo,
            N * S, D, D, D, D, D, 0, 0, 0, 1.0f, 0);
        mfma_gemm<SM_PLANES2, SM_PLANES2, EPI_SPLIT, 4, false, 4><<<g, blk, 0, stream>>>(
            k_hi, k_lo, WK_hi, WK_lo, nullptr, nullptr, nullptr, nullptr, wk_hi, wk_lo,
            N * S, D, D, D, D, D, 0, 0, 0, 1.0f, 0);
        mfma_gemm<SM_PLANES1, SM_PLANES1, EPI_F16T, 4, false, 4><<<g, blk, 0, stream>>>(
            v_hi, nullptr, WV_hi, nullptr, nullptr, nullptr, nullptr, nullptr, wvT_hi, nullptr,
            N * S, D, D, D, D, 0, 0, 0, 0, 1.0f, 11 /* tsShift: S=2048 */);
    }
    // ---- scores: Sc[n] = wq[n] @ wk[n]^T (f32) + fused column-stat partials ----
    {
        dim3 g(S / 128, S / 128, N);
        mfma_gemm<SM_PLANES2, SM_PLANES2, EPI_F32, 4, true, 4><<<g, blk, 0, stream>>>(
            wq_hi, wq_lo, wk_hi, wk_lo, nullptr, nullptr, pm, ps, Sc, nullptr,
            S, S, D, D, D, S, (long)S * D, (long)S * D, (long)S * S, 1.0f, 0);
    }
    // ---- combine partials -> statM, statR ----
    {
        dim3 gB(S / 64, N);
        stats_combine_kernel<<<gB, dim3(64), 0, stream>>>(pm, ps, statM, statR, S);
    }
    // ---- out[n] = (P[n] @ wvT[n]^T)/1024, P = exp(Sc-m)*r computed in fragment path ----
    {
        dim3 g(D / 128, S / 128, N);
        mfma_gemm<SM_EXPF32, SM_PLANES1, EPI_F32, 0, false, 2><<<g, blk, 0, stream>>>(
            Sc, nullptr, wvT_hi, nullptr, statM, statR, nullptr, nullptr, out, nullptr,
            S, D, S, S, S, D, (long)S * S, (long)S * D, (long)S * D, 1.0f / (float)D, 0);
    }
}